// Round 2
// baseline (198.697 us; speedup 1.0000x reference)
//
#include <hip/hip_runtime.h>
#include <hip/hip_bf16.h>

#define NEV 131072
#define NF 128
#define NG 64
#define KIN 192      // NF + NG
#define NH 512
#define NOUT 256     // N_BRANCHES * NF
#define BM 64
#define NTHREADS 512

typedef __bf16 bf16x8 __attribute__((ext_vector_type(8)));
typedef __bf16 bf16x4 __attribute__((ext_vector_type(4)));
typedef float f32x4 __attribute__((ext_vector_type(4)));

// Swizzled LDS byte offsets. XOR of (row&7)<<4 permutes 16B slots within each
// 128B group -> breaks the all-lanes-same-bank pattern of stride-384/1024 rows.
__device__ __forceinline__ int a_off(int r, int cb) { return r * 384 + (cb ^ ((r & 7) << 4)); }
__device__ __forceinline__ int h_off(int r, int cb) { return r * 1024 + (cb ^ ((r & 7) << 4)); }

// ---- weight convert+transpose: W1[192][512] -> w1t[512][192] bf16,
//      W2[512][256] -> w2t[256][512] bf16
__global__ void convert_w(const float* __restrict__ W1, const float* __restrict__ W2,
                          __bf16* __restrict__ w1t, __bf16* __restrict__ w2t) {
    int t = blockIdx.x * blockDim.x + threadIdx.x;
    if (t < KIN * NH) {
        int k = t / NH, n = t % NH;
        w1t[(size_t)n * KIN + k] = (__bf16)W1[t];
    }
    int u = t - KIN * NH;
    if (u >= 0 && u < NH * NOUT) {
        int k = u / NOUT, n = u % NOUT;
        w2t[(size_t)n * NH + k] = (__bf16)W2[u];
    }
}

template <bool TW>
__global__ __launch_bounds__(NTHREADS, 2) void fused_mlp(
        const float* __restrict__ x, const float* __restrict__ gf,
        const __bf16* __restrict__ w1t, const float* __restrict__ W1f,
        const float* __restrict__ b1,
        const __bf16* __restrict__ w2t, const float* __restrict__ W2f,
        const float* __restrict__ b2,
        const int* __restrict__ idx,
        float* __restrict__ out) {
    __shared__ __align__(16) unsigned char smem[65536];  // A-tile then reused as h-tile

    const int tid = threadIdx.x;
    const int wid = tid >> 6;          // 0..7
    const int lane = tid & 63;
    const int lg = lane >> 4;          // lane-group 0..3
    const int lr = lane & 15;
    const int row0 = blockIdx.x * BM;

    // ---- PREFETCH: all GEMM1 B-fragments into registers (96 VGPRs).
    // Issued first so their L2 latency overlaps the whole staging phase.
    bf16x8 b1r[KIN / 32][4];
#pragma unroll
    for (int kk = 0; kk < KIN / 32; ++kk) {
#pragma unroll
        for (int n = 0; n < 4; ++n) {
            int col = wid * 64 + n * 16 + lr;
            if (TW) {
                b1r[kk][n] = *(const bf16x8*)(w1t + (size_t)col * KIN + kk * 32 + lg * 8);
            } else {
                const float* wc = W1f + (size_t)(kk * 32 + lg * 8) * NH + col;
#pragma unroll
                for (int i = 0; i < 8; ++i) b1r[kk][n][i] = (__bf16)wc[(size_t)i * NH];
            }
        }
    }
    // bias prefetch
    float bb1[4];
#pragma unroll
    for (int n = 0; n < 4; ++n) bb1[n] = b1[wid * 64 + n * 16 + lr];
    float bb2[2];
#pragma unroll
    for (int n = 0; n < 2; ++n) bb2[n] = b2[wid * 32 + n * 16 + lr];

    // ---- stage A = [x | gf] as bf16 into LDS (swizzled); fuse the x -> out copy
    const float4* x4 = (const float4*)x;
    const float4* g4 = (const float4*)gf;
    float4* o4 = (float4*)out;
    for (int q = tid; q < BM * (NF / 4); q += NTHREADS) {
        int r = q >> 5, c4 = q & 31;
        int e = row0 + r;
        int p = idx[e];
        float4 v = x4[(size_t)e * (NF / 4) + c4];
        o4[(size_t)e * (NF / 4) + c4] = v;            // out[0:NEV] = x
        float4 vs = (p == e) ? v : x4[(size_t)p * (NF / 4) + c4];
        bf16x4 tb = {(__bf16)vs.x, (__bf16)vs.y, (__bf16)vs.z, (__bf16)vs.w};
        *(bf16x4*)(smem + a_off(r, c4 * 8)) = tb;
    }
    for (int q = tid; q < BM * (NG / 4); q += NTHREADS) {
        int r = q >> 4, c4 = q & 15;
        int e = row0 + r;
        int p = idx[e] & (NEV - 1);                   // parents_idxs % n_events
        float4 vs = g4[(size_t)p * (NG / 4) + c4];
        bf16x4 tb = {(__bf16)vs.x, (__bf16)vs.y, (__bf16)vs.z, (__bf16)vs.w};
        *(bf16x4*)(smem + a_off(r, 256 + c4 * 8)) = tb;
    }
    __syncthreads();

    // ---- GEMM1: A(64x192) @ W1(192x512); wave owns 64 hidden cols.
    // Pure ds_read + MFMA (B already in registers).
    f32x4 acc1[4][4] = {};
#pragma unroll
    for (int kk = 0; kk < KIN / 32; ++kk) {
        int kbyte = kk * 64 + lg * 16;
        bf16x8 a[4];
#pragma unroll
        for (int m = 0; m < 4; ++m)
            a[m] = *(const bf16x8*)(smem + a_off(m * 16 + lr, kbyte));
#pragma unroll
        for (int n = 0; n < 4; ++n)
#pragma unroll
            for (int m = 0; m < 4; ++m)
                acc1[m][n] = __builtin_amdgcn_mfma_f32_16x16x32_bf16(a[m], b1r[kk][n], acc1[m][n], 0, 0, 0);
    }

    // ---- PREFETCH: all GEMM2 B-fragments (128 VGPRs; B1 regs are dead now).
    // Latency hides behind epilogue1 + barrier + GEMM2's first ds_reads.
    bf16x8 b2r[NH / 32][2];
#pragma unroll
    for (int kk = 0; kk < NH / 32; ++kk) {
#pragma unroll
        for (int n = 0; n < 2; ++n) {
            int col = wid * 32 + n * 16 + lr;
            if (TW) {
                b2r[kk][n] = *(const bf16x8*)(w2t + (size_t)col * NH + kk * 32 + lg * 8);
            } else {
                const float* wc = W2f + (size_t)(kk * 32 + lg * 8) * NOUT + col;
#pragma unroll
                for (int i = 0; i < 8; ++i) b2r[kk][n][i] = (__bf16)wc[(size_t)i * NOUT];
            }
        }
    }

    __syncthreads();  // everyone done reading A; smem becomes h

    // ---- epilogue1: bias + leaky_relu -> h bf16 in LDS (swizzled)
#pragma unroll
    for (int n = 0; n < 4; ++n) {
        int col = wid * 64 + n * 16 + lr;
#pragma unroll
        for (int m = 0; m < 4; ++m) {
#pragma unroll
            for (int i = 0; i < 4; ++i) {
                int row = m * 16 + lg * 4 + i;
                float v = acc1[m][n][i] + bb1[n];
                v = (v >= 0.f) ? v : 0.01f * v;
                *(__bf16*)(smem + h_off(row, col * 2)) = (__bf16)v;
            }
        }
    }
    __syncthreads();

    // ---- GEMM2: h(64x512) @ W2(512x256); wave owns 32 out cols
    f32x4 acc2[4][2] = {};
#pragma unroll
    for (int kk = 0; kk < NH / 32; ++kk) {
        int kbyte = kk * 64 + lg * 16;
        bf16x8 a[4];
#pragma unroll
        for (int m = 0; m < 4; ++m)
            a[m] = *(const bf16x8*)(smem + h_off(m * 16 + lr, kbyte));
#pragma unroll
        for (int n = 0; n < 2; ++n)
#pragma unroll
            for (int m = 0; m < 4; ++m)
                acc2[m][n] = __builtin_amdgcn_mfma_f32_16x16x32_bf16(a[m], b2r[kk][n], acc2[m][n], 0, 0, 0);
    }

    // ---- epilogue2: bias + branch-split scatter to out
#pragma unroll
    for (int n = 0; n < 2; ++n) {
        int col = wid * 32 + n * 16 + lr;
        int br = col >> 7;       // branch index
        int f = col & 127;
        float* obase = out + (size_t)(NEV * (1 + br)) * NF + f;
#pragma unroll
        for (int m = 0; m < 4; ++m) {
#pragma unroll
            for (int i = 0; i < 4; ++i) {
                int row = m * 16 + lg * 4 + i;
                int e = row0 + row;
                obase[(size_t)e * NF] = acc2[m][n][i] + bb2[n];
            }
        }
    }
}

extern "C" void kernel_launch(void* const* d_in, const int* in_sizes, int n_in,
                              void* d_out, int out_size, void* d_ws, size_t ws_size,
                              hipStream_t stream) {
    const float* x  = (const float*)d_in[0];
    const float* gf = (const float*)d_in[1];
    const float* W1 = (const float*)d_in[2];
    const float* b1 = (const float*)d_in[3];
    const float* W2 = (const float*)d_in[4];
    const float* b2 = (const float*)d_in[5];
    const int*  idx = (const int*)d_in[6];
    float* out = (float*)d_out;

    const size_t wbytes = (size_t)(KIN * NH + NH * NOUT) * sizeof(__bf16);
    const int nblocks = NEV / BM;

    if (ws_size >= wbytes) {
        __bf16* w1t = (__bf16*)d_ws;
        __bf16* w2t = w1t + KIN * NH;
        int tot = KIN * NH + NH * NOUT;
        convert_w<<<(tot + 511) / 512, 512, 0, stream>>>(W1, W2, w1t, w2t);
        fused_mlp<true><<<nblocks, NTHREADS, 0, stream>>>(x, gf, w1t, nullptr, b1,
                                                          w2t, nullptr, b2, idx, out);
    } else {
        fused_mlp<false><<<nblocks, NTHREADS, 0, stream>>>(x, gf, nullptr, W1, b1,
                                                           nullptr, W2, b2, idx, out);
    }
}

// Round 3
// 142.770 us; speedup vs baseline: 1.3917x; 1.3917x over previous
//
#include <hip/hip_runtime.h>
#include <hip/hip_bf16.h>

#define NEV 131072
#define NF 128
#define NG 64
#define KIN 192      // NF + NG
#define NH 512
#define NOUT 256     // N_BRANCHES * NF
#define BM 64
#define NTHREADS 512

typedef __bf16 bf16x8 __attribute__((ext_vector_type(8)));
typedef __bf16 bf16x4 __attribute__((ext_vector_type(4)));
typedef float f32x4 __attribute__((ext_vector_type(4)));

// Swizzled LDS byte offsets. XOR of (row&7)<<4 permutes 16B slots within each
// 128B group -> breaks the all-lanes-same-bank pattern of stride-384/1024 rows.
__device__ __forceinline__ int a_off(int r, int cb) { return r * 384 + (cb ^ ((r & 7) << 4)); }
__device__ __forceinline__ int h_off(int r, int cb) { return r * 1024 + (cb ^ ((r & 7) << 4)); }

// ---- weight pre-pack into per-wave FRAGMENT ORDER (bf16).
// w1p: fragment (wid,kk,n) at ((wid*6+kk)*4+n)*512 .. +512, lane-major, 8 elems/lane.
//      One bf16x8 load per wave = 64 lanes x 16B = 1KB contiguous.
// w2p: fragment (wid,kk,n) at ((wid*16+kk)*2+n)*512 .. +512, same scheme.
__global__ void pack_w(const float* __restrict__ W1, const float* __restrict__ W2,
                       __bf16* __restrict__ w1p, __bf16* __restrict__ w2p) {
    int t = blockIdx.x * blockDim.x + threadIdx.x;
    if (t < KIN * NH) {
        int j = t & 7;
        int lane = (t >> 3) & 63;
        int n = (t >> 9) & 3;
        int r = t >> 11;          // wid*6 + kk
        int kk = r % 6;
        int wid = r / 6;
        int lg = lane >> 4, lr = lane & 15;
        int k = kk * 32 + lg * 8 + j;
        int col = wid * 64 + n * 16 + lr;
        w1p[t] = (__bf16)W1[(size_t)k * NH + col];
    } else {
        int u = t - KIN * NH;
        if (u < NH * NOUT) {
            int j = u & 7;
            int lane = (u >> 3) & 63;
            int n = (u >> 9) & 1;
            int r = u >> 10;      // wid*16 + kk
            int kk = r & 15;
            int wid = r >> 4;
            int lg = lane >> 4, lr = lane & 15;
            int k = kk * 32 + lg * 8 + j;
            int col = wid * 32 + n * 16 + lr;
            w2p[u] = (__bf16)W2[(size_t)k * NOUT + col];
        }
    }
}

template <bool TW>
__global__ __launch_bounds__(NTHREADS, 2) void fused_mlp(
        const float* __restrict__ x, const float* __restrict__ gf,
        const __bf16* __restrict__ w1p, const float* __restrict__ W1f,
        const float* __restrict__ b1,
        const __bf16* __restrict__ w2p, const float* __restrict__ W2f,
        const float* __restrict__ b2,
        const int* __restrict__ idx,
        float* __restrict__ out) {
    __shared__ __align__(16) unsigned char smem[65536];  // A-tile then reused as h-tile

    const int tid = threadIdx.x;
    const int wid = tid >> 6;          // 0..7
    const int lane = tid & 63;
    const int lg = lane >> 4;          // lane-group 0..3
    const int lr = lane & 15;
    const int row0 = blockIdx.x * BM;

    // ---- PREFETCH: all GEMM1 B-fragments (packed, contiguous 1KB/wave-load).
    bf16x8 b1r[KIN / 32][4];
#pragma unroll
    for (int kk = 0; kk < KIN / 32; ++kk) {
#pragma unroll
        for (int n = 0; n < 4; ++n) {
            if (TW) {
                b1r[kk][n] = *(const bf16x8*)(w1p + (size_t)(((wid * 6 + kk) * 4 + n) * 64 + lane) * 8);
            } else {
                int col = wid * 64 + n * 16 + lr;
                const float* wc = W1f + (size_t)(kk * 32 + lg * 8) * NH + col;
#pragma unroll
                for (int i = 0; i < 8; ++i) b1r[kk][n][i] = (__bf16)wc[(size_t)i * NH];
            }
        }
    }
    // bias prefetch
    float bb1[4];
#pragma unroll
    for (int n = 0; n < 4; ++n) bb1[n] = b1[wid * 64 + n * 16 + lr];
    float bb2[2];
#pragma unroll
    for (int n = 0; n < 2; ++n) bb2[n] = b2[wid * 32 + n * 16 + lr];

    // ---- stage A = [x | gf] as bf16 into LDS (swizzled); fuse the x -> out copy
    const float4* x4 = (const float4*)x;
    const float4* g4 = (const float4*)gf;
    float4* o4 = (float4*)out;
    for (int q = tid; q < BM * (NF / 4); q += NTHREADS) {
        int r = q >> 5, c4 = q & 31;
        int e = row0 + r;
        int p = idx[e];
        float4 v = x4[(size_t)e * (NF / 4) + c4];
        o4[(size_t)e * (NF / 4) + c4] = v;            // out[0:NEV] = x
        float4 vs = (p == e) ? v : x4[(size_t)p * (NF / 4) + c4];
        bf16x4 tb = {(__bf16)vs.x, (__bf16)vs.y, (__bf16)vs.z, (__bf16)vs.w};
        *(bf16x4*)(smem + a_off(r, c4 * 8)) = tb;
    }
    for (int q = tid; q < BM * (NG / 4); q += NTHREADS) {
        int r = q >> 4, c4 = q & 15;
        int e = row0 + r;
        int p = idx[e] & (NEV - 1);                   // parents_idxs % n_events
        float4 vs = g4[(size_t)p * (NG / 4) + c4];
        bf16x4 tb = {(__bf16)vs.x, (__bf16)vs.y, (__bf16)vs.z, (__bf16)vs.w};
        *(bf16x4*)(smem + a_off(r, 256 + c4 * 8)) = tb;
    }
    __syncthreads();

    // ---- GEMM1: A(64x192) @ W1(192x512); wave owns 64 hidden cols.
    f32x4 acc1[4][4] = {};
#pragma unroll
    for (int kk = 0; kk < KIN / 32; ++kk) {
        int kbyte = kk * 64 + lg * 16;
        bf16x8 a[4];
#pragma unroll
        for (int m = 0; m < 4; ++m)
            a[m] = *(const bf16x8*)(smem + a_off(m * 16 + lr, kbyte));
#pragma unroll
        for (int n = 0; n < 4; ++n)
#pragma unroll
            for (int m = 0; m < 4; ++m)
                acc1[m][n] = __builtin_amdgcn_mfma_f32_16x16x32_bf16(a[m], b1r[kk][n], acc1[m][n], 0, 0, 0);
    }

    // ---- PREFETCH: all GEMM2 B-fragments (packed, contiguous 1KB/wave-load).
    bf16x8 b2r[NH / 32][2];
#pragma unroll
    for (int kk = 0; kk < NH / 32; ++kk) {
#pragma unroll
        for (int n = 0; n < 2; ++n) {
            if (TW) {
                b2r[kk][n] = *(const bf16x8*)(w2p + (size_t)(((wid * 16 + kk) * 2 + n) * 64 + lane) * 8);
            } else {
                int col = wid * 32 + n * 16 + lr;
                const float* wc = W2f + (size_t)(kk * 32 + lg * 8) * NOUT + col;
#pragma unroll
                for (int i = 0; i < 8; ++i) b2r[kk][n][i] = (__bf16)wc[(size_t)i * NOUT];
            }
        }
    }

    __syncthreads();  // everyone done reading A; smem becomes h

    // ---- epilogue1: bias + leaky_relu -> h bf16 in LDS (swizzled)
#pragma unroll
    for (int n = 0; n < 4; ++n) {
        int col = wid * 64 + n * 16 + lr;
#pragma unroll
        for (int m = 0; m < 4; ++m) {
#pragma unroll
            for (int i = 0; i < 4; ++i) {
                int row = m * 16 + lg * 4 + i;
                float v = acc1[m][n][i] + bb1[n];
                v = (v >= 0.f) ? v : 0.01f * v;
                *(__bf16*)(smem + h_off(row, col * 2)) = (__bf16)v;
            }
        }
    }
    __syncthreads();

    // ---- GEMM2: h(64x512) @ W2(512x256); wave owns 32 out cols
    f32x4 acc2[4][2] = {};
#pragma unroll
    for (int kk = 0; kk < NH / 32; ++kk) {
        int kbyte = kk * 64 + lg * 16;
        bf16x8 a[4];
#pragma unroll
        for (int m = 0; m < 4; ++m)
            a[m] = *(const bf16x8*)(smem + h_off(m * 16 + lr, kbyte));
#pragma unroll
        for (int n = 0; n < 2; ++n)
#pragma unroll
            for (int m = 0; m < 4; ++m)
                acc2[m][n] = __builtin_amdgcn_mfma_f32_16x16x32_bf16(a[m], b2r[kk][n], acc2[m][n], 0, 0, 0);
    }

    // ---- epilogue2: bias + branch-split scatter to out
#pragma unroll
    for (int n = 0; n < 2; ++n) {
        int col = wid * 32 + n * 16 + lr;
        int br = col >> 7;       // branch index
        int f = col & 127;
        float* obase = out + (size_t)(NEV * (1 + br)) * NF + f;
#pragma unroll
        for (int m = 0; m < 4; ++m) {
#pragma unroll
            for (int i = 0; i < 4; ++i) {
                int row = m * 16 + lg * 4 + i;
                int e = row0 + row;
                obase[(size_t)e * NF] = acc2[m][n][i] + bb2[n];
            }
        }
    }
}

extern "C" void kernel_launch(void* const* d_in, const int* in_sizes, int n_in,
                              void* d_out, int out_size, void* d_ws, size_t ws_size,
                              hipStream_t stream) {
    const float* x  = (const float*)d_in[0];
    const float* gf = (const float*)d_in[1];
    const float* W1 = (const float*)d_in[2];
    const float* b1 = (const float*)d_in[3];
    const float* W2 = (const float*)d_in[4];
    const float* b2 = (const float*)d_in[5];
    const int*  idx = (const int*)d_in[6];
    float* out = (float*)d_out;

    const size_t wbytes = (size_t)(KIN * NH + NH * NOUT) * sizeof(__bf16);
    const int nblocks = NEV / BM;

    if (ws_size >= wbytes) {
        __bf16* w1p = (__bf16*)d_ws;
        __bf16* w2p = w1p + KIN * NH;
        int tot = KIN * NH + NH * NOUT;
        pack_w<<<(tot + 511) / 512, 512, 0, stream>>>(W1, W2, w1p, w2p);
        fused_mlp<true><<<nblocks, NTHREADS, 0, stream>>>(x, gf, w1p, nullptr, b1,
                                                          w2p, nullptr, b2, idx, out);
    } else {
        fused_mlp<false><<<nblocks, NTHREADS, 0, stream>>>(x, gf, nullptr, W1, b1,
                                                           nullptr, W2, b2, idx, out);
    }
}